// Round 3
// baseline (1000.750 us; speedup 1.0000x reference)
//
#include <hip/hip_runtime.h>
#include <stdint.h>

typedef unsigned short u16;
typedef __attribute__((ext_vector_type(8))) __bf16 bf16x8;
typedef __attribute__((ext_vector_type(8))) u16 u16x8;
typedef __attribute__((ext_vector_type(4))) float f32x4;

#define HID 2048
#define INTER 5632
#define TOKENS 8192

__device__ __forceinline__ u16 f2bf(float f) {
  uint32_t u = __builtin_bit_cast(uint32_t, f);
  u += 0x7fffu + ((u >> 16) & 1u);
  return (u16)(u >> 16);
}

__device__ __forceinline__ void gld_lds16(const u16* g, u16* l) {
  __builtin_amdgcn_global_load_lds(
      (const __attribute__((address_space(1))) unsigned int*)g,
      (__attribute__((address_space(3))) unsigned int*)l, 16, 0, 0);
}

// ---------------- conversion kernels (unchanged, working) ----------------

__global__ void k_cvt_x(const float* __restrict__ in, u16* __restrict__ out) {
  size_t i = (size_t)blockIdx.x * 256 + threadIdx.x;
  const float4* p = (const float4*)(in + i * 8);
  float4 a = p[0], b = p[1];
  u16x8 o;
  o[0] = f2bf(a.x); o[1] = f2bf(a.y); o[2] = f2bf(a.z); o[3] = f2bf(a.w);
  o[4] = f2bf(b.x); o[5] = f2bf(b.y); o[6] = f2bf(b.z); o[7] = f2bf(b.w);
  *(u16x8*)(out + i * 8) = o;
}

__global__ void k_transpose(const float* __restrict__ in, u16* __restrict__ out,
                            int R, int C) {
  __shared__ float t[32][33];
  int c0 = blockIdx.x * 32, r0 = blockIdx.y * 32;
  int tx = threadIdx.x, ty = threadIdx.y;
#pragma unroll
  for (int r = 0; r < 4; ++r) {
    int i = ty + r * 8;
    t[i][tx] = in[(size_t)(r0 + i) * C + c0 + tx];
  }
  __syncthreads();
#pragma unroll
  for (int r = 0; r < 4; ++r) {
    int i = ty + r * 8;
    out[(size_t)(c0 + i) * R + r0 + tx] = f2bf(t[tx][i]);
  }
}

// ---------------- 256^2 8-phase GEMM machinery ----------------
// Panels: [row 0..255][k 0..63] bf16, row stride 128B, stored with chunk-XOR
// swizzle: physical 16B-chunk = logical_chunk ^ (row&7). Staging writes LINEAR
// LDS (global_load_lds requirement) from an inverse-swizzled GLOBAL source.

// stage 128 rows (one half-tile) = 2 x gld_lds16 per thread (512 thr).
// dst: u16* panel-half base. srcBase: global row0 of this half. stride: K elems.
#define STAGE(dst, srcBase, stride, kt)                                        \
  do {                                                                         \
    const int _k0 = (kt) * 64;                                                 \
    _Pragma("unroll") for (int _r = 0; _r < 2; ++_r) {                         \
      const int _prow = _r * 64 + wid * 8 + srow;                              \
      const u16* _src = (srcBase) + (size_t)_prow * (stride) + _k0 +           \
                        ((schunk ^ (_prow & 7)) * 8);                          \
      gld_lds16(_src, (dst) + _prow * 64 + schunk * 8);                        \
    }                                                                          \
  } while (0)

// read 4 A-frags (m-half mh) x 2 k-slices from swizzled panel
#define LOAD_A(bufp, mh)                                                       \
  do {                                                                         \
    _Pragma("unroll") for (int _jj = 0; _jj < 4; ++_jj) {                      \
      const int _row = ((mh)*4 + _jj) * 32 + wm * 16 + cb;                     \
      _Pragma("unroll") for (int _ks = 0; _ks < 2; ++_ks) {                    \
        const int _ch = (_ks * 4 + hi) ^ (cb & 7);                             \
        aF[_jj][_ks] = *(const bf16x8*)((bufp) + _row * 64 + _ch * 8);         \
      }                                                                        \
    }                                                                          \
  } while (0)

// read 2 B-frags (n-half nh) x 2 k-slices
#define LOAD_B(bufp, nh)                                                       \
  do {                                                                         \
    _Pragma("unroll") for (int _nn = 0; _nn < 2; ++_nn) {                      \
      const int _row = ((nh)*2 + _nn) * 64 + wn * 16 + cb;                     \
      _Pragma("unroll") for (int _ks = 0; _ks < 2; ++_ks) {                    \
        const int _ch = (_ks * 4 + hi) ^ (cb & 7);                             \
        bF[_nn][_ks] = *(const bf16x8*)((bufp) + _row * 64 + _ch * 8);         \
      }                                                                        \
    }                                                                          \
  } while (0)

#define MMA_Q(mh, nh)                                                          \
  do {                                                                         \
    _Pragma("unroll") for (int _ks = 0; _ks < 2; ++_ks)                        \
    _Pragma("unroll") for (int _jj = 0; _jj < 4; ++_jj)                        \
    _Pragma("unroll") for (int _nn = 0; _nn < 2; ++_nn)                        \
      acc[(mh)*4 + _jj][(nh)*2 + _nn] =                                        \
          __builtin_amdgcn_mfma_f32_16x16x32_bf16(                             \
              aF[_jj][_ks], bF[_nn][_ks], acc[(mh)*4 + _jj][(nh)*2 + _nn],     \
              0, 0, 0);                                                        \
  } while (0)

// one K-tile = 4 phases. Stage order for t+1: A0,B0,A1,B1 (one per phase).
// Waits: end-P1 vmcnt(4) [forces B1(t) done], end-P3 vmcnt(2) [forces
// A0,B0,A1(t+1) done]. Never 0 except last-tile drain.
#define KTILE_BODY(bufA, bufB, nA, nB, gA0, gB0, gA1, gB1, STRIDE, hn, tn)     \
  do {                                                                         \
    /* P0: quad(0,0) */                                                        \
    if (hn) STAGE(nA, gA0, STRIDE, tn);                                        \
    LOAD_A(bufA, 0); LOAD_B(bufB, 0);                                          \
    __builtin_amdgcn_s_barrier();                                              \
    __builtin_amdgcn_s_setprio(1); MMA_Q(0, 0); __builtin_amdgcn_s_setprio(0); \
    __builtin_amdgcn_s_barrier();                                              \
    /* P1: quad(1,0) */                                                        \
    if (hn) STAGE(nB, gB0, STRIDE, tn);                                        \
    LOAD_A(bufA, 1);                                                           \
    __builtin_amdgcn_s_barrier();                                              \
    __builtin_amdgcn_s_setprio(1); MMA_Q(1, 0); __builtin_amdgcn_s_setprio(0); \
    __builtin_amdgcn_sched_barrier(0);                                         \
    if (hn) asm volatile("s_waitcnt vmcnt(4)" ::: "memory");                   \
    else    asm volatile("s_waitcnt vmcnt(0)" ::: "memory");                   \
    __builtin_amdgcn_s_barrier();                                              \
    /* P2: quad(1,1) */                                                        \
    if (hn) STAGE((nA) + 128 * 64, gA1, STRIDE, tn);                           \
    LOAD_B(bufB, 1);                                                           \
    __builtin_amdgcn_s_barrier();                                              \
    __builtin_amdgcn_s_setprio(1); MMA_Q(1, 1); __builtin_amdgcn_s_setprio(0); \
    __builtin_amdgcn_s_barrier();                                              \
    /* P3: quad(0,1) */                                                        \
    if (hn) STAGE((nB) + 128 * 64, gB1, STRIDE, tn);                           \
    LOAD_A(bufA, 0);                                                           \
    __builtin_amdgcn_s_barrier();                                              \
    __builtin_amdgcn_s_setprio(1); MMA_Q(0, 1); __builtin_amdgcn_s_setprio(0); \
    __builtin_amdgcn_sched_barrier(0);                                         \
    if (hn) asm volatile("s_waitcnt vmcnt(2)" ::: "memory");                   \
    __builtin_amdgcn_s_barrier();                                              \
  } while (0)

// ---------------- GEMM1: x @ W1 fused SwiGLU, tile 256M x (128 gate+128 up) --
__global__ __launch_bounds__(512, 2) void k_gemm1_8ph(
    const u16* __restrict__ xb, const u16* __restrict__ w1t,
    u16* __restrict__ hid) {
  __shared__ __align__(16) u16 sA[2][256 * 64];
  __shared__ __align__(16) u16 sB[2][256 * 64];
  const int NT = HID / 64;  // 32
  // bijective XCD swizzle: 1408 blocks, 176/XCD
  const int o = blockIdx.x;
  const int swz = (o & 7) * 176 + (o >> 3);
  const int brow = (swz / 44) * 256, bcol = (swz % 44) * 128;

  const int tid = threadIdx.x, lane = tid & 63, wid = tid >> 6;
  const int wm = wid >> 2, wn = wid & 3;
  const int cb = lane & 15, hi = lane >> 4;
  const int srow = lane >> 3, schunk = lane & 7;

  f32x4 acc[8][4] = {};
  bf16x8 aF[4][2], bF[2][2];

  const u16* gA0 = xb + (size_t)brow * HID;
  const u16* gA1 = gA0 + (size_t)128 * HID;
  const u16* gB0 = w1t + (size_t)bcol * HID;            // gate rows
  const u16* gB1 = w1t + (size_t)(INTER + bcol) * HID;  // up rows

  // prologue: tile 0, order A0,B0,A1,B1
  STAGE(sA[0], gA0, HID, 0);
  STAGE(sB[0], gB0, HID, 0);
  STAGE(sA[0] + 128 * 64, gA1, HID, 0);
  STAGE(sB[0] + 128 * 64, gB1, HID, 0);
  asm volatile("s_waitcnt vmcnt(2)" ::: "memory");
  __builtin_amdgcn_s_barrier();

  for (int t = 0; t < NT; ++t) {
    u16* bufA = sA[t & 1];
    u16* bufB = sB[t & 1];
    u16* nA = sA[(t & 1) ^ 1];
    u16* nB = sB[(t & 1) ^ 1];
    const bool hn = (t + 1 < NT);
    KTILE_BODY(bufA, bufB, nA, nB, gA0, gB0, gA1, gB1, HID, hn, t + 1);
  }

  // epilogue: silu(gate)*up -> hid bf16. n-frags 0,1 = gate; 2,3 = up (same cols)
#pragma unroll
  for (int j = 0; j < 8; ++j)
#pragma unroll
    for (int nn = 0; nn < 2; ++nn) {
      const int col = bcol + nn * 64 + wn * 16 + cb;
#pragma unroll
      for (int i = 0; i < 4; ++i) {
        const int row = brow + j * 32 + wm * 16 + hi * 4 + i;
        float g = acc[j][nn][i], u = acc[j][nn + 2][i];
        float h = g / (1.0f + __expf(-g)) * u;
        hid[(size_t)row * INTER + col] = f2bf(h);
      }
    }
}

// ---------------- GEMM2: hidden @ W2, tile 256x256 ----------------
__global__ __launch_bounds__(512, 2) void k_gemm2_8ph(
    const u16* __restrict__ hid, const u16* __restrict__ w2t,
    float* __restrict__ out) {
  __shared__ __align__(16) u16 sA[2][256 * 64];
  __shared__ __align__(16) u16 sB[2][256 * 64];
  const int NT = INTER / 64;  // 88
  // bijective XCD swizzle: 256 blocks, 32/XCD
  const int o = blockIdx.x;
  const int swz = (o & 7) * 32 + (o >> 3);
  const int brow = (swz / 8) * 256, bcol = (swz % 8) * 256;

  const int tid = threadIdx.x, lane = tid & 63, wid = tid >> 6;
  const int wm = wid >> 2, wn = wid & 3;
  const int cb = lane & 15, hi = lane >> 4;
  const int srow = lane >> 3, schunk = lane & 7;

  f32x4 acc[8][4] = {};
  bf16x8 aF[4][2], bF[2][2];

  const u16* gA0 = hid + (size_t)brow * INTER;
  const u16* gA1 = gA0 + (size_t)128 * INTER;
  const u16* gB0 = w2t + (size_t)bcol * INTER;
  const u16* gB1 = w2t + (size_t)(bcol + 128) * INTER;

  STAGE(sA[0], gA0, INTER, 0);
  STAGE(sB[0], gB0, INTER, 0);
  STAGE(sA[0] + 128 * 64, gA1, INTER, 0);
  STAGE(sB[0] + 128 * 64, gB1, INTER, 0);
  asm volatile("s_waitcnt vmcnt(2)" ::: "memory");
  __builtin_amdgcn_s_barrier();

  for (int t = 0; t < NT; ++t) {
    u16* bufA = sA[t & 1];
    u16* bufB = sB[t & 1];
    u16* nA = sA[(t & 1) ^ 1];
    u16* nB = sB[(t & 1) ^ 1];
    const bool hn = (t + 1 < NT);
    KTILE_BODY(bufA, bufB, nA, nB, gA0, gB0, gA1, gB1, INTER, hn, t + 1);
  }

#pragma unroll
  for (int j = 0; j < 8; ++j)
#pragma unroll
    for (int n = 0; n < 4; ++n) {
      const int col = bcol + n * 64 + wn * 16 + cb;
#pragma unroll
      for (int i = 0; i < 4; ++i) {
        const int row = brow + j * 32 + wm * 16 + hi * 4 + i;
        out[(size_t)row * HID + col] = acc[j][n][i];
      }
    }
}

// ---------------- launch ----------------

extern "C" void kernel_launch(void* const* d_in, const int* in_sizes, int n_in,
                              void* d_out, int out_size, void* d_ws, size_t ws_size,
                              hipStream_t stream) {
  const float* x  = (const float*)d_in[0];   // [8192][2048]
  const float* w1 = (const float*)d_in[1];   // [2048][11264]
  const float* w2 = (const float*)d_in[2];   // [5632][2048]
  float* out = (float*)d_out;

  const size_t off_xb  = 0;                   // 33554432
  const size_t off_w1t = 33554432;            // +46137344
  const size_t off_w2t = off_w1t + 46137344;  // +23068672
  const size_t off_hid = off_w2t + 23068672;  // +92274688
  const size_t need    = off_hid + 92274688;
  if (ws_size < need) return;

  char* ws = (char*)d_ws;
  u16* xb  = (u16*)(ws + off_xb);
  u16* w1t = (u16*)(ws + off_w1t);
  u16* w2t = (u16*)(ws + off_w2t);
  u16* hid = (u16*)(ws + off_hid);

  k_cvt_x<<<TOKENS * HID / 8 / 256, 256, 0, stream>>>(x, xb);
  dim3 tb(32, 8);
  k_transpose<<<dim3((2 * INTER) / 32, HID / 32), tb, 0, stream>>>(w1, w1t, HID, 2 * INTER);
  k_transpose<<<dim3(HID / 32, INTER / 32), tb, 0, stream>>>(w2, w2t, INTER, HID);

  k_gemm1_8ph<<<(TOKENS / 256) * (INTER / 128), 512, 0, stream>>>(xb, w1t, hid);
  k_gemm2_8ph<<<(TOKENS / 256) * (HID / 256), 512, 0, stream>>>(hid, w2t, out);
}

// Round 5
// 866.853 us; speedup vs baseline: 1.1545x; 1.1545x over previous
//
#include <hip/hip_runtime.h>
#include <stdint.h>

typedef unsigned short u16;
typedef __attribute__((ext_vector_type(8))) __bf16 bf16x8;
typedef __attribute__((ext_vector_type(8))) u16 u16x8;
typedef __attribute__((ext_vector_type(4))) float f32x4;

#define HID 2048
#define INTER 5632
#define TOKENS 8192

__device__ __forceinline__ u16 f2bf(float f) {
  uint32_t u = __builtin_bit_cast(uint32_t, f);
  u += 0x7fffu + ((u >> 16) & 1u);
  return (u16)(u >> 16);
}

__device__ __forceinline__ void gld_lds16(const u16* g, u16* l) {
  __builtin_amdgcn_global_load_lds(
      (const __attribute__((address_space(1))) unsigned int*)g,
      (__attribute__((address_space(3))) unsigned int*)l, 16, 0, 0);
}

// ---------------- conversion kernels ----------------

__global__ void k_cvt_x(const float* __restrict__ in, u16* __restrict__ out) {
  size_t i = (size_t)blockIdx.x * 256 + threadIdx.x;
  const float4* p = (const float4*)(in + i * 8);
  float4 a = p[0], b = p[1];
  u16x8 o;
  o[0] = f2bf(a.x); o[1] = f2bf(a.y); o[2] = f2bf(a.z); o[3] = f2bf(a.w);
  o[4] = f2bf(b.x); o[5] = f2bf(b.y); o[6] = f2bf(b.z); o[7] = f2bf(b.w);
  *(u16x8*)(out + i * 8) = o;
}

// 64x64-tile transpose: in [R][C] f32 -> out [C][R] bf16.
// float4 loads, u16x8 stores; LDS pad 65 -> 2-way max conflict (free).
__global__ __launch_bounds__(256) void k_transpose64(
    const float* __restrict__ in, u16* __restrict__ out, int R, int C) {
  __shared__ float t[64][65];
  int c0 = blockIdx.x * 64, r0 = blockIdx.y * 64;
  int tid = threadIdx.x;
  int tx = tid & 15, ry = tid >> 4;
#pragma unroll
  for (int r = 0; r < 4; ++r) {
    int row = r * 16 + ry;
    float4 v = *(const float4*)(in + (size_t)(r0 + row) * C + c0 + tx * 4);
    t[row][tx * 4 + 0] = v.x; t[row][tx * 4 + 1] = v.y;
    t[row][tx * 4 + 2] = v.z; t[row][tx * 4 + 3] = v.w;
  }
  __syncthreads();
  int cc = tid >> 2, seg = tid & 3;
#pragma unroll
  for (int h = 0; h < 2; ++h) {
    int rr0 = seg * 16 + h * 8;
    u16x8 o;
#pragma unroll
    for (int j = 0; j < 8; ++j) o[j] = f2bf(t[rr0 + j][cc]);
    *(u16x8*)(out + (size_t)(c0 + cc) * R + r0 + rr0) = o;
  }
}

// ---------------- 256^2 8-phase GEMM machinery ----------------
// Panels [256 rows][64 k] bf16, swizzled: physical 16B-chunk = logical ^ (row&7).
// Staging writes LINEAR LDS from inverse-swizzled GLOBAL source (rule 21).

#define STAGE(dst, srcBase, stride, kt)                                        \
  do {                                                                         \
    const int _k0 = (kt) * 64;                                                 \
    _Pragma("unroll") for (int _r = 0; _r < 2; ++_r) {                         \
      const int _prow = _r * 64 + wid * 8 + srow;                              \
      const u16* _src = (srcBase) + (size_t)_prow * (stride) + _k0 +           \
                        ((schunk ^ (_prow & 7)) * 8);                          \
      gld_lds16(_src, (dst) + _prow * 64 + schunk * 8);                        \
    }                                                                          \
  } while (0)

#define LOAD_A(bufp, mh)                                                       \
  do {                                                                         \
    _Pragma("unroll") for (int _jj = 0; _jj < 4; ++_jj) {                      \
      const int _row = ((mh)*4 + _jj) * 32 + wm * 16 + cb;                     \
      _Pragma("unroll") for (int _ks = 0; _ks < 2; ++_ks) {                    \
        const int _ch = (_ks * 4 + hi) ^ (cb & 7);                             \
        aF[_jj][_ks] = *(const bf16x8*)((bufp) + _row * 64 + _ch * 8);         \
      }                                                                        \
    }                                                                          \
  } while (0)

#define LOAD_B(bufp, nh)                                                       \
  do {                                                                         \
    _Pragma("unroll") for (int _nn = 0; _nn < 2; ++_nn) {                      \
      const int _row = ((nh)*2 + _nn) * 64 + wn * 16 + cb;                     \
      _Pragma("unroll") for (int _ks = 0; _ks < 2; ++_ks) {                    \
        const int _ch = (_ks * 4 + hi) ^ (cb & 7);                             \
        bF[_nn][_ks] = *(const bf16x8*)((bufp) + _row * 64 + _ch * 8);         \
      }                                                                        \
    }                                                                          \
  } while (0)

#define MMA_Q(mh, nh)                                                          \
  do {                                                                         \
    _Pragma("unroll") for (int _ks = 0; _ks < 2; ++_ks)                        \
    _Pragma("unroll") for (int _jj = 0; _jj < 4; ++_jj)                        \
    _Pragma("unroll") for (int _nn = 0; _nn < 2; ++_nn)                        \
      acc[(mh)*4 + _jj][(nh)*2 + _nn] =                                        \
          __builtin_amdgcn_mfma_f32_16x16x32_bf16(                             \
              aF[_jj][_ks], bF[_nn][_ks], acc[(mh)*4 + _jj][(nh)*2 + _nn],     \
              0, 0, 0);                                                        \
  } while (0)

// One K-tile = 4 phases. Stage issue for t+1: P0: A0'+B0', P1: A1', P2: B1'.
// Derived waits (per-thread stream, 2 loads/stage, steady state outstanding=8
// at each wait): end-P0 vmcnt(6) -> A1(t) done; end-P1 vmcnt(6) -> B1(t) done;
// end-P3 vmcnt(4) -> A0',B0' done.  Every stage gets >=3 phases of cover.
// Last tile (hn=0): end-P0 vmcnt(2), end-P1 vmcnt(0), end-P3 none.
#define KTILE_BODY(bufA, bufB, nA, nB, gA0, gB0, gA1, gB1, STRIDE, hn, tn)     \
  do {                                                                         \
    /* P0: quad(0,0) */                                                        \
    if (hn) { STAGE(nA, gA0, STRIDE, tn); STAGE(nB, gB0, STRIDE, tn); }        \
    LOAD_A(bufA, 0); LOAD_B(bufB, 0);                                          \
    __builtin_amdgcn_s_barrier();                                              \
    __builtin_amdgcn_s_setprio(1); MMA_Q(0, 0); __builtin_amdgcn_s_setprio(0); \
    __builtin_amdgcn_sched_barrier(0);                                         \
    if (hn) asm volatile("s_waitcnt vmcnt(6)" ::: "memory");                   \
    else    asm volatile("s_waitcnt vmcnt(2)" ::: "memory");                   \
    __builtin_amdgcn_s_barrier();                                              \
    /* P1: quad(1,0) */                                                        \
    if (hn) STAGE((nA) + 128 * 64, gA1, STRIDE, tn);                           \
    LOAD_A(bufA, 1);                                                           \
    __builtin_amdgcn_s_barrier();                                              \
    __builtin_amdgcn_s_setprio(1); MMA_Q(1, 0); __builtin_amdgcn_s_setprio(0); \
    __builtin_amdgcn_sched_barrier(0);                                         \
    if (hn) asm volatile("s_waitcnt vmcnt(6)" ::: "memory");                   \
    else    asm volatile("s_waitcnt vmcnt(0)" ::: "memory");                   \
    __builtin_amdgcn_s_barrier();                                              \
    /* P2: quad(1,1) */                                                        \
    if (hn) STAGE((nB) + 128 * 64, gB1, STRIDE, tn);                           \
    LOAD_B(bufB, 1);                                                           \
    __builtin_amdgcn_s_barrier();                                              \
    __builtin_amdgcn_s_setprio(1); MMA_Q(1, 1); __builtin_amdgcn_s_setprio(0); \
    __builtin_amdgcn_s_barrier();                                              \
    /* P3: quad(0,1) */                                                        \
    LOAD_A(bufA, 0);                                                           \
    __builtin_amdgcn_s_barrier();                                              \
    __builtin_amdgcn_s_setprio(1); MMA_Q(0, 1); __builtin_amdgcn_s_setprio(0); \
    __builtin_amdgcn_sched_barrier(0);                                         \
    if (hn) asm volatile("s_waitcnt vmcnt(4)" ::: "memory");                   \
    __builtin_amdgcn_s_barrier();                                              \
  } while (0)

// ---------------- GEMM1: x @ W1 fused SwiGLU, 256M x (128 gate + 128 up) ----
__global__ __launch_bounds__(512, 2) void k_gemm1_8ph(
    const u16* __restrict__ xb, const u16* __restrict__ w1t,
    u16* __restrict__ hid) {
  __shared__ __align__(16) u16 sA[2][256 * 64];
  __shared__ __align__(16) u16 sB[2][256 * 64];
  const int NT = HID / 64;  // 32
  const int o = blockIdx.x;                      // 1408 blocks = 8 * 176
  const int swz = (o & 7) * 176 + (o >> 3);
  const int brow = (swz / 44) * 256, bcol = (swz % 44) * 128;

  const int tid = threadIdx.x, lane = tid & 63, wid = tid >> 6;
  const int wm = wid >> 2, wn = wid & 3;
  const int cb = lane & 15, hi = lane >> 4;
  const int srow = lane >> 3, schunk = lane & 7;

  f32x4 acc[8][4] = {};
  bf16x8 aF[4][2], bF[2][2];

  const u16* gA0 = xb + (size_t)brow * HID;
  const u16* gA1 = gA0 + (size_t)128 * HID;
  const u16* gB0 = w1t + (size_t)bcol * HID;            // gate rows
  const u16* gB1 = w1t + (size_t)(INTER + bcol) * HID;  // up rows

  // prologue: stage tile 0, wait A0,B0 only (A1,B1 covered by loop waits)
  STAGE(sA[0], gA0, HID, 0);
  STAGE(sB[0], gB0, HID, 0);
  STAGE(sA[0] + 128 * 64, gA1, HID, 0);
  STAGE(sB[0] + 128 * 64, gB1, HID, 0);
  __builtin_amdgcn_sched_barrier(0);
  asm volatile("s_waitcnt vmcnt(4)" ::: "memory");
  __builtin_amdgcn_s_barrier();

  for (int t = 0; t < NT; ++t) {
    u16* bufA = sA[t & 1];
    u16* bufB = sB[t & 1];
    u16* nA = sA[(t & 1) ^ 1];
    u16* nB = sB[(t & 1) ^ 1];
    const bool hn = (t + 1 < NT);
    KTILE_BODY(bufA, bufB, nA, nB, gA0, gB0, gA1, gB1, HID, hn, t + 1);
  }

  // epilogue: silu(gate)*up -> hid bf16 (n-frags 0,1 = gate; 2,3 = up)
#pragma unroll
  for (int j = 0; j < 8; ++j)
#pragma unroll
    for (int nn = 0; nn < 2; ++nn) {
      const int col = bcol + nn * 64 + wn * 16 + cb;
#pragma unroll
      for (int i = 0; i < 4; ++i) {
        const int row = brow + j * 32 + wm * 16 + hi * 4 + i;
        float g = acc[j][nn][i], u = acc[j][nn + 2][i];
        float h = g / (1.0f + __expf(-g)) * u;
        hid[(size_t)row * INTER + col] = f2bf(h);
      }
    }
}

// ---------------- GEMM2: hidden @ W2, 256x256 ----------------
__global__ __launch_bounds__(512, 2) void k_gemm2_8ph(
    const u16* __restrict__ hid, const u16* __restrict__ w2t,
    float* __restrict__ out) {
  __shared__ __align__(16) u16 sA[2][256 * 64];
  __shared__ __align__(16) u16 sB[2][256 * 64];
  const int NT = INTER / 64;  // 88
  const int o = blockIdx.x;                      // 256 blocks = 8 * 32
  const int swz = (o & 7) * 32 + (o >> 3);
  const int brow = (swz / 8) * 256, bcol = (swz % 8) * 256;

  const int tid = threadIdx.x, lane = tid & 63, wid = tid >> 6;
  const int wm = wid >> 2, wn = wid & 3;
  const int cb = lane & 15, hi = lane >> 4;
  const int srow = lane >> 3, schunk = lane & 7;

  f32x4 acc[8][4] = {};
  bf16x8 aF[4][2], bF[2][2];

  const u16* gA0 = hid + (size_t)brow * INTER;
  const u16* gA1 = gA0 + (size_t)128 * INTER;
  const u16* gB0 = w2t + (size_t)bcol * INTER;
  const u16* gB1 = w2t + (size_t)(bcol + 128) * INTER;

  STAGE(sA[0], gA0, INTER, 0);
  STAGE(sB[0], gB0, INTER, 0);
  STAGE(sA[0] + 128 * 64, gA1, INTER, 0);
  STAGE(sB[0] + 128 * 64, gB1, INTER, 0);
  __builtin_amdgcn_sched_barrier(0);
  asm volatile("s_waitcnt vmcnt(4)" ::: "memory");
  __builtin_amdgcn_s_barrier();

  for (int t = 0; t < NT; ++t) {
    u16* bufA = sA[t & 1];
    u16* bufB = sB[t & 1];
    u16* nA = sA[(t & 1) ^ 1];
    u16* nB = sB[(t & 1) ^ 1];
    const bool hn = (t + 1 < NT);
    KTILE_BODY(bufA, bufB, nA, nB, gA0, gB0, gA1, gB1, INTER, hn, t + 1);
  }

#pragma unroll
  for (int j = 0; j < 8; ++j)
#pragma unroll
    for (int n = 0; n < 4; ++n) {
      const int col = bcol + n * 64 + wn * 16 + cb;
#pragma unroll
      for (int i = 0; i < 4; ++i) {
        const int row = brow + j * 32 + wm * 16 + hi * 4 + i;
        out[(size_t)row * HID + col] = acc[j][n][i];
      }
    }
}

// ---------------- launch ----------------

extern "C" void kernel_launch(void* const* d_in, const int* in_sizes, int n_in,
                              void* d_out, int out_size, void* d_ws, size_t ws_size,
                              hipStream_t stream) {
  const float* x  = (const float*)d_in[0];   // [8192][2048]
  const float* w1 = (const float*)d_in[1];   // [2048][11264]
  const float* w2 = (const float*)d_in[2];   // [5632][2048]
  float* out = (float*)d_out;

  const size_t off_xb  = 0;                   // 33554432
  const size_t off_w1t = 33554432;            // +46137344
  const size_t off_w2t = off_w1t + 46137344;  // +23068672
  const size_t off_hid = off_w2t + 23068672;  // +92274688
  const size_t need    = off_hid + 92274688;
  if (ws_size < need) return;

  char* ws = (char*)d_ws;
  u16* xb  = (u16*)(ws + off_xb);
  u16* w1t = (u16*)(ws + off_w1t);
  u16* w2t = (u16*)(ws + off_w2t);
  u16* hid = (u16*)(ws + off_hid);

  k_cvt_x<<<TOKENS * HID / 8 / 256, 256, 0, stream>>>(x, xb);
  k_transpose64<<<dim3((2 * INTER) / 64, HID / 64), 256, 0, stream>>>(w1, w1t, HID, 2 * INTER);
  k_transpose64<<<dim3(HID / 64, INTER / 64), 256, 0, stream>>>(w2, w2t, INTER, HID);

  k_gemm1_8ph<<<(TOKENS / 256) * (INTER / 128), 512, 0, stream>>>(xb, w1t, hid);
  k_gemm2_8ph<<<(TOKENS / 256) * (HID / 256), 512, 0, stream>>>(hid, w2t, out);
}

// Round 6
// 830.992 us; speedup vs baseline: 1.2043x; 1.0432x over previous
//
#include <hip/hip_runtime.h>
#include <stdint.h>

typedef unsigned short u16;
typedef __attribute__((ext_vector_type(8))) __bf16 bf16x8;
typedef __attribute__((ext_vector_type(8))) u16 u16x8;
typedef __attribute__((ext_vector_type(4))) float f32x4;

#define HID 2048
#define INTER 5632
#define TOKENS 8192

__device__ __forceinline__ u16 f2bf(float f) {
  uint32_t u = __builtin_bit_cast(uint32_t, f);
  u += 0x7fffu + ((u >> 16) & 1u);
  return (u16)(u >> 16);
}

__device__ __forceinline__ void gld_lds16(const u16* g, u16* l) {
  __builtin_amdgcn_global_load_lds(
      (const __attribute__((address_space(1))) unsigned int*)g,
      (__attribute__((address_space(3))) unsigned int*)l, 16, 0, 0);
}

// ---------------- conversion kernels (validated round 5) ----------------

__global__ void k_cvt_x(const float* __restrict__ in, u16* __restrict__ out) {
  size_t i = (size_t)blockIdx.x * 256 + threadIdx.x;
  const float4* p = (const float4*)(in + i * 8);
  float4 a = p[0], b = p[1];
  u16x8 o;
  o[0] = f2bf(a.x); o[1] = f2bf(a.y); o[2] = f2bf(a.z); o[3] = f2bf(a.w);
  o[4] = f2bf(b.x); o[5] = f2bf(b.y); o[6] = f2bf(b.z); o[7] = f2bf(b.w);
  *(u16x8*)(out + i * 8) = o;
}

__global__ __launch_bounds__(256) void k_transpose64(
    const float* __restrict__ in, u16* __restrict__ out, int R, int C) {
  __shared__ float t[64][65];
  int c0 = blockIdx.x * 64, r0 = blockIdx.y * 64;
  int tid = threadIdx.x;
  int tx = tid & 15, ry = tid >> 4;
#pragma unroll
  for (int r = 0; r < 4; ++r) {
    int row = r * 16 + ry;
    float4 v = *(const float4*)(in + (size_t)(r0 + row) * C + c0 + tx * 4);
    t[row][tx * 4 + 0] = v.x; t[row][tx * 4 + 1] = v.y;
    t[row][tx * 4 + 2] = v.z; t[row][tx * 4 + 3] = v.w;
  }
  __syncthreads();
  int cc = tid >> 2, seg = tid & 3;
#pragma unroll
  for (int h = 0; h < 2; ++h) {
    int rr0 = seg * 16 + h * 8;
    u16x8 o;
#pragma unroll
    for (int j = 0; j < 8; ++j) o[j] = f2bf(t[rr0 + j][cc]);
    *(u16x8*)(out + (size_t)(c0 + cc) * R + r0 + rr0) = o;
  }
}

// ---------------- GEMM1: proven 2-barrier 128-tile + fused SwiGLU ----------
// (round-2 kernel verbatim: 431 us / 877 TF measured)
__global__ __launch_bounds__(256, 2) void k_gemm1(
    const u16* __restrict__ xb, const u16* __restrict__ w1t,
    u16* __restrict__ hid) {
  __shared__ __align__(16) u16 sA[128 * 64];
  __shared__ __align__(16) u16 sG[64 * 64];
  __shared__ __align__(16) u16 sU[64 * 64];
  const int K = HID;
  int brow = blockIdx.y * 128, bcol = blockIdx.x * 64;
  int tid = threadIdx.x, lane = tid & 63, wid = tid >> 6;
  int wm = wid >> 1, wn = wid & 1;
  f32x4 accg[4][2] = {}, accu[4][2] = {};
  const u16* gA = xb + (size_t)brow * K;
  const u16* gG = w1t + (size_t)bcol * K;
  const u16* gU = w1t + (size_t)(bcol + INTER) * K;
  int tr = tid >> 3;
  int tc = (tid & 7) * 8;
  int cb = lane & 15, kb = (lane >> 4) * 8;

  for (int kt = 0; kt < K / 64; ++kt) {
    int k0 = kt * 64;
#pragma unroll
    for (int r = 0; r < 4; ++r) {
      int row = r * 32 + tr;
      gld_lds16(gA + (size_t)row * K + k0 + tc, &sA[row * 64 + tc]);
    }
#pragma unroll
    for (int r = 0; r < 2; ++r) {
      int row = r * 32 + tr;
      gld_lds16(gG + (size_t)row * K + k0 + tc, &sG[row * 64 + tc]);
      gld_lds16(gU + (size_t)row * K + k0 + tc, &sU[row * 64 + tc]);
    }
    __syncthreads();
#pragma unroll
    for (int ks = 0; ks < 2; ++ks) {
      int kk = ks * 32 + kb;
      bf16x8 af[4];
#pragma unroll
      for (int m = 0; m < 4; ++m)
        af[m] = *(const bf16x8*)&sA[(wm * 64 + m * 16 + cb) * 64 + kk];
#pragma unroll
      for (int n = 0; n < 2; ++n) {
        bf16x8 bg = *(const bf16x8*)&sG[(wn * 32 + n * 16 + cb) * 64 + kk];
        bf16x8 bu = *(const bf16x8*)&sU[(wn * 32 + n * 16 + cb) * 64 + kk];
#pragma unroll
        for (int m = 0; m < 4; ++m) {
          accg[m][n] = __builtin_amdgcn_mfma_f32_16x16x32_bf16(af[m], bg, accg[m][n], 0, 0, 0);
          accu[m][n] = __builtin_amdgcn_mfma_f32_16x16x32_bf16(af[m], bu, accu[m][n], 0, 0, 0);
        }
      }
    }
    __syncthreads();
  }
  int rb = (lane >> 4) * 4;
#pragma unroll
  for (int m = 0; m < 4; ++m)
#pragma unroll
    for (int n = 0; n < 2; ++n) {
      int col = bcol + wn * 32 + n * 16 + cb;
#pragma unroll
      for (int i = 0; i < 4; ++i) {
        int row = brow + wm * 64 + m * 16 + rb + i;
        float g = accg[m][n][i], u = accu[m][n][i];
        float h = g / (1.0f + __expf(-g)) * u;
        hid[(size_t)row * INTER + col] = f2bf(h);
      }
    }
}

// ---------------- GEMM2 v3: 256x256 8-phase, 2 waits/K-tile ----------------
// Panels [256][64] bf16, chunk-XOR swizzle (physical chunk = logical ^ row&7);
// staging = linear LDS dest + inverse-swizzled global source (rule 21).

#define STAGE(dst, srcBase, stride, kt)                                        \
  do {                                                                         \
    const int _k0 = (kt) * 64;                                                 \
    _Pragma("unroll") for (int _r = 0; _r < 2; ++_r) {                         \
      const int _prow = _r * 64 + wid * 8 + srow;                              \
      const u16* _src = (srcBase) + (size_t)_prow * (stride) + _k0 +           \
                        ((schunk ^ (_prow & 7)) * 8);                          \
      gld_lds16(_src, (dst) + _prow * 64 + schunk * 8);                        \
    }                                                                          \
  } while (0)

#define LOAD_A(bufp, mh)                                                       \
  do {                                                                         \
    _Pragma("unroll") for (int _jj = 0; _jj < 4; ++_jj) {                      \
      const int _row = ((mh)*4 + _jj) * 32 + wm * 16 + cb;                     \
      _Pragma("unroll") for (int _ks = 0; _ks < 2; ++_ks) {                    \
        const int _ch = (_ks * 4 + hi) ^ (cb & 7);                             \
        aF[_jj][_ks] = *(const bf16x8*)((bufp) + _row * 64 + _ch * 8);         \
      }                                                                        \
    }                                                                          \
  } while (0)

#define LOAD_B(bufp, nh)                                                       \
  do {                                                                         \
    _Pragma("unroll") for (int _nn = 0; _nn < 2; ++_nn) {                      \
      const int _row = ((nh)*2 + _nn) * 64 + wn * 16 + cb;                     \
      _Pragma("unroll") for (int _ks = 0; _ks < 2; ++_ks) {                    \
        const int _ch = (_ks * 4 + hi) ^ (cb & 7);                             \
        bF[_nn][_ks] = *(const bf16x8*)((bufp) + _row * 64 + _ch * 8);         \
      }                                                                        \
    }                                                                          \
  } while (0)

#define MMA_Q(mh, nh)                                                          \
  do {                                                                         \
    _Pragma("unroll") for (int _ks = 0; _ks < 2; ++_ks)                        \
    _Pragma("unroll") for (int _jj = 0; _jj < 4; ++_jj)                        \
    _Pragma("unroll") for (int _nn = 0; _nn < 2; ++_nn)                        \
      acc[(mh)*4 + _jj][(nh)*2 + _nn] =                                        \
          __builtin_amdgcn_mfma_f32_16x16x32_bf16(                             \
              aF[_jj][_ks], bF[_nn][_ks], acc[(mh)*4 + _jj][(nh)*2 + _nn],     \
              0, 0, 0);                                                        \
  } while (0)

// Stage issue (tile t, for t+1): P0: A0'+B0' (4 loads), P1: A1'+B1' (4).
// Invariant: entering each tile, outstanding = 4 = {A1,B1 of current buffer}.
// end-P0 vmcnt(4): outstanding 4+4=8, forces A1,B1 (read P1/P2) -> 3-phase
// cover. end-P3 vmcnt(4): outstanding 4+4=8, forces A0',B0' (read next P0) ->
// 3-phase cover; survivors {A1',B1'} = 4, invariant closes. Last tile:
// end-P0 vmcnt(0) drains; no other waits.
__global__ __launch_bounds__(512, 2) void k_gemm2_v3(
    const u16* __restrict__ hid, const u16* __restrict__ w2t,
    float* __restrict__ out) {
  __shared__ __align__(16) u16 sA[2][256 * 64];
  __shared__ __align__(16) u16 sB[2][256 * 64];
  const int NT = INTER / 64;  // 88
  const int brow = blockIdx.y * 256, bcol = blockIdx.x * 256;

  const int tid = threadIdx.x, lane = tid & 63, wid = tid >> 6;
  const int wm = wid >> 2, wn = wid & 3;
  const int cb = lane & 15, hi = lane >> 4;
  const int srow = lane >> 3, schunk = lane & 7;

  f32x4 acc[8][4] = {};
  bf16x8 aF[4][2], bF[2][2];

  const u16* gA0 = hid + (size_t)brow * INTER;
  const u16* gA1 = gA0 + (size_t)128 * INTER;
  const u16* gB0 = w2t + (size_t)bcol * INTER;
  const u16* gB1 = w2t + (size_t)(bcol + 128) * INTER;

  // prologue: stage tile 0 (A0,B0,A1,B1), force A0,B0; A1,B1 stay in flight
  STAGE(sA[0], gA0, INTER, 0);
  STAGE(sB[0], gB0, INTER, 0);
  STAGE(sA[0] + 128 * 64, gA1, INTER, 0);
  STAGE(sB[0] + 128 * 64, gB1, INTER, 0);
  __builtin_amdgcn_sched_barrier(0);
  asm volatile("s_waitcnt vmcnt(4)" ::: "memory");
  __builtin_amdgcn_s_barrier();

  for (int t = 0; t < NT; ++t) {
    u16* bufA = sA[t & 1];
    u16* bufB = sB[t & 1];
    u16* nA = sA[(t & 1) ^ 1];
    u16* nB = sB[(t & 1) ^ 1];
    const bool hn = (t + 1 < NT);

    // P0: quad(0,0); stage A0',B0'
    if (hn) { STAGE(nA, gA0, INTER, t + 1); STAGE(nB, gB0, INTER, t + 1); }
    LOAD_A(bufA, 0); LOAD_B(bufB, 0);
    __builtin_amdgcn_s_barrier();
    __builtin_amdgcn_s_setprio(1); MMA_Q(0, 0); __builtin_amdgcn_s_setprio(0);
    __builtin_amdgcn_sched_barrier(0);
    if (hn) asm volatile("s_waitcnt vmcnt(4)" ::: "memory");
    else    asm volatile("s_waitcnt vmcnt(0)" ::: "memory");
    __builtin_amdgcn_s_barrier();

    // P1: quad(1,0); stage A1',B1'
    if (hn) {
      STAGE(nA + 128 * 64, gA1, INTER, t + 1);
      STAGE(nB + 128 * 64, gB1, INTER, t + 1);
    }
    LOAD_A(bufA, 1);
    __builtin_amdgcn_s_barrier();
    __builtin_amdgcn_s_setprio(1); MMA_Q(1, 0); __builtin_amdgcn_s_setprio(0);
    __builtin_amdgcn_s_barrier();

    // P2: quad(1,1); no stage
    LOAD_B(bufB, 1);
    __builtin_amdgcn_s_barrier();
    __builtin_amdgcn_s_setprio(1); MMA_Q(1, 1); __builtin_amdgcn_s_setprio(0);
    __builtin_amdgcn_s_barrier();

    // P3: quad(0,1); re-read A half0; end-of-tile wait
    LOAD_A(bufA, 0);
    __builtin_amdgcn_s_barrier();
    __builtin_amdgcn_s_setprio(1); MMA_Q(0, 1); __builtin_amdgcn_s_setprio(0);
    __builtin_amdgcn_sched_barrier(0);
    if (hn) asm volatile("s_waitcnt vmcnt(4)" ::: "memory");
    __builtin_amdgcn_s_barrier();
  }

#pragma unroll
  for (int j = 0; j < 8; ++j)
#pragma unroll
    for (int n = 0; n < 4; ++n) {
      const int col = bcol + n * 64 + wn * 16 + cb;
#pragma unroll
      for (int i = 0; i < 4; ++i) {
        const int row = brow + j * 32 + wm * 16 + hi * 4 + i;
        out[(size_t)row * HID + col] = acc[j][n][i];
      }
    }
}

// ---------------- launch ----------------

extern "C" void kernel_launch(void* const* d_in, const int* in_sizes, int n_in,
                              void* d_out, int out_size, void* d_ws, size_t ws_size,
                              hipStream_t stream) {
  const float* x  = (const float*)d_in[0];   // [8192][2048]
  const float* w1 = (const float*)d_in[1];   // [2048][11264]
  const float* w2 = (const float*)d_in[2];   // [5632][2048]
  float* out = (float*)d_out;

  const size_t off_xb  = 0;                   // 33554432
  const size_t off_w1t = 33554432;            // +46137344
  const size_t off_w2t = off_w1t + 46137344;  // +23068672
  const size_t off_hid = off_w2t + 23068672;  // +92274688
  const size_t need    = off_hid + 92274688;
  if (ws_size < need) return;

  char* ws = (char*)d_ws;
  u16* xb  = (u16*)(ws + off_xb);
  u16* w1t = (u16*)(ws + off_w1t);
  u16* w2t = (u16*)(ws + off_w2t);
  u16* hid = (u16*)(ws + off_hid);

  k_cvt_x<<<TOKENS * HID / 8 / 256, 256, 0, stream>>>(x, xb);
  k_transpose64<<<dim3((2 * INTER) / 64, HID / 64), 256, 0, stream>>>(w1, w1t, HID, 2 * INTER);
  k_transpose64<<<dim3(HID / 64, INTER / 64), 256, 0, stream>>>(w2, w2t, INTER, HID);

  k_gemm1<<<dim3(INTER / 64, TOKENS / 128), 256, 0, stream>>>(xb, w1t, hid);
  k_gemm2_v3<<<dim3(HID / 256, TOKENS / 256), 512, 0, stream>>>(hid, w2t, out);
}

// Round 8
// 808.766 us; speedup vs baseline: 1.2374x; 1.0275x over previous
//
#include <hip/hip_runtime.h>
#include <stdint.h>

typedef unsigned short u16;
typedef __attribute__((ext_vector_type(8))) __bf16 bf16x8;
typedef __attribute__((ext_vector_type(8))) u16 u16x8;
typedef __attribute__((ext_vector_type(4))) float f32x4;

#define HID 2048
#define INTER 5632
#define TOKENS 8192
#define HALF (128 * 64)

__device__ __forceinline__ u16 f2bf(float f) {
  uint32_t u = __builtin_bit_cast(uint32_t, f);
  u += 0x7fffu + ((u >> 16) & 1u);
  return (u16)(u >> 16);
}

__device__ __forceinline__ void gld_lds16(const u16* g, u16* l) {
  __builtin_amdgcn_global_load_lds(
      (const __attribute__((address_space(1))) unsigned int*)g,
      (__attribute__((address_space(3))) unsigned int*)l, 16, 0, 0);
}

// ---------------- conversion kernels (validated) ----------------

__global__ void k_cvt_x(const float* __restrict__ in, u16* __restrict__ out) {
  size_t i = (size_t)blockIdx.x * 256 + threadIdx.x;
  const float4* p = (const float4*)(in + i * 8);
  float4 a = p[0], b = p[1];
  u16x8 o;
  o[0] = f2bf(a.x); o[1] = f2bf(a.y); o[2] = f2bf(a.z); o[3] = f2bf(a.w);
  o[4] = f2bf(b.x); o[5] = f2bf(b.y); o[6] = f2bf(b.z); o[7] = f2bf(b.w);
  *(u16x8*)(out + i * 8) = o;
}

__global__ __launch_bounds__(256) void k_transpose64(
    const float* __restrict__ in, u16* __restrict__ out, int R, int C) {
  __shared__ float t[64][65];
  int c0 = blockIdx.x * 64, r0 = blockIdx.y * 64;
  int tid = threadIdx.x;
  int tx = tid & 15, ry = tid >> 4;
#pragma unroll
  for (int r = 0; r < 4; ++r) {
    int row = r * 16 + ry;
    float4 v = *(const float4*)(in + (size_t)(r0 + row) * C + c0 + tx * 4);
    t[row][tx * 4 + 0] = v.x; t[row][tx * 4 + 1] = v.y;
    t[row][tx * 4 + 2] = v.z; t[row][tx * 4 + 3] = v.w;
  }
  __syncthreads();
  int cc = tid >> 2, seg = tid & 3;
#pragma unroll
  for (int h = 0; h < 2; ++h) {
    int rr0 = seg * 16 + h * 8;
    u16x8 o;
#pragma unroll
    for (int j = 0; j < 8; ++j) o[j] = f2bf(t[rr0 + j][cc]);
    *(u16x8*)(out + (size_t)(c0 + cc) * R + r0 + rr0) = o;
  }
}

// ---------------- GEMM1: proven 2-barrier 128-tile + fused SwiGLU ----------
// (round-2 kernel verbatim: 426-431 us / ~880 TF measured)
__global__ __launch_bounds__(256, 2) void k_gemm1(
    const u16* __restrict__ xb, const u16* __restrict__ w1t,
    u16* __restrict__ hid) {
  __shared__ __align__(16) u16 sA[128 * 64];
  __shared__ __align__(16) u16 sG[64 * 64];
  __shared__ __align__(16) u16 sU[64 * 64];
  const int K = HID;
  int brow = blockIdx.y * 128, bcol = blockIdx.x * 64;
  int tid = threadIdx.x, lane = tid & 63, wid = tid >> 6;
  int wm = wid >> 1, wn = wid & 1;
  f32x4 accg[4][2] = {}, accu[4][2] = {};
  const u16* gA = xb + (size_t)brow * K;
  const u16* gG = w1t + (size_t)bcol * K;
  const u16* gU = w1t + (size_t)(bcol + INTER) * K;
  int tr = tid >> 3;
  int tc = (tid & 7) * 8;
  int cb = lane & 15, kb = (lane >> 4) * 8;

  for (int kt = 0; kt < K / 64; ++kt) {
    int k0 = kt * 64;
#pragma unroll
    for (int r = 0; r < 4; ++r) {
      int row = r * 32 + tr;
      gld_lds16(gA + (size_t)row * K + k0 + tc, &sA[row * 64 + tc]);
    }
#pragma unroll
    for (int r = 0; r < 2; ++r) {
      int row = r * 32 + tr;
      gld_lds16(gG + (size_t)row * K + k0 + tc, &sG[row * 64 + tc]);
      gld_lds16(gU + (size_t)row * K + k0 + tc, &sU[row * 64 + tc]);
    }
    __syncthreads();
#pragma unroll
    for (int ks = 0; ks < 2; ++ks) {
      int kk = ks * 32 + kb;
      bf16x8 af[4];
#pragma unroll
      for (int m = 0; m < 4; ++m)
        af[m] = *(const bf16x8*)&sA[(wm * 64 + m * 16 + cb) * 64 + kk];
#pragma unroll
      for (int n = 0; n < 2; ++n) {
        bf16x8 bg = *(const bf16x8*)&sG[(wn * 32 + n * 16 + cb) * 64 + kk];
        bf16x8 bu = *(const bf16x8*)&sU[(wn * 32 + n * 16 + cb) * 64 + kk];
#pragma unroll
        for (int m = 0; m < 4; ++m) {
          accg[m][n] = __builtin_amdgcn_mfma_f32_16x16x32_bf16(af[m], bg, accg[m][n], 0, 0, 0);
          accu[m][n] = __builtin_amdgcn_mfma_f32_16x16x32_bf16(af[m], bu, accu[m][n], 0, 0, 0);
        }
      }
    }
    __syncthreads();
  }
  int rb = (lane >> 4) * 4;
#pragma unroll
  for (int m = 0; m < 4; ++m)
#pragma unroll
    for (int n = 0; n < 2; ++n) {
      int col = bcol + wn * 32 + n * 16 + cb;
#pragma unroll
      for (int i = 0; i < 4; ++i) {
        int row = brow + wm * 64 + m * 16 + rb + i;
        float g = accg[m][n][i], u = accu[m][n][i];
        float h = g / (1.0f + __expf(-g)) * u;
        hid[(size_t)row * INTER + col] = f2bf(h);
      }
    }
}

// ---------------- GEMM2 m201-faithful clone ----------------
// Rolling half-slot ring: stage 1 half-tile/phase into the slot freed the
// previous phase, at ~2-tile lead; ONE vmcnt(6) per K-tile (14->6) forcing
// exactly tile t+1's 4 half-tiles; stage->force distance 3-6 phases.
// Quadrant order (0,0),(0,1),(1,1),(1,0); per-phase ds_reads {12,4,8,4}.

#define STAGE(dst, srcBase, stride, kt)                                        \
  do {                                                                         \
    const int _k0 = (kt) * 64;                                                 \
    _Pragma("unroll") for (int _r = 0; _r < 2; ++_r) {                         \
      const int _prow = _r * 64 + wid * 8 + srow;                              \
      const u16* _src = (srcBase) + (size_t)_prow * (stride) + _k0 +           \
                        ((schunk ^ (_prow & 7)) * 8);                          \
      gld_lds16(_src, (dst) + _prow * 64 + schunk * 8);                        \
    }                                                                          \
  } while (0)

#define LOAD_A(bufp, mh)                                                       \
  do {                                                                         \
    _Pragma("unroll") for (int _jj = 0; _jj < 4; ++_jj) {                      \
      const int _row = ((mh)*4 + _jj) * 32 + wm * 16 + cb;                     \
      _Pragma("unroll") for (int _ks = 0; _ks < 2; ++_ks) {                    \
        const int _ch = (_ks * 4 + hi) ^ (cb & 7);                             \
        aF[_jj][_ks] = *(const bf16x8*)((bufp) + _row * 64 + _ch * 8);         \
      }                                                                        \
    }                                                                          \
  } while (0)

#define LOAD_B(bufp, nh)                                                       \
  do {                                                                         \
    _Pragma("unroll") for (int _nn = 0; _nn < 2; ++_nn) {                      \
      const int _row = ((nh)*2 + _nn) * 64 + wn * 16 + cb;                     \
      _Pragma("unroll") for (int _ks = 0; _ks < 2; ++_ks) {                    \
        const int _ch = (_ks * 4 + hi) ^ (cb & 7);                             \
        bF[_nn][_ks] = *(const bf16x8*)((bufp) + _row * 64 + _ch * 8);         \
      }                                                                        \
    }                                                                          \
  } while (0)

#define MMA_Q(mh, nh)                                                          \
  do {                                                                         \
    _Pragma("unroll") for (int _ks = 0; _ks < 2; ++_ks)                        \
    _Pragma("unroll") for (int _jj = 0; _jj < 4; ++_jj)                        \
    _Pragma("unroll") for (int _nn = 0; _nn < 2; ++_nn)                        \
      acc[(mh)*4 + _jj][(nh)*2 + _nn] =                                        \
          __builtin_amdgcn_mfma_f32_16x16x32_bf16(                             \
              aF[_jj][_ks], bF[_nn][_ks], acc[(mh)*4 + _jj][(nh)*2 + _nn],     \
              0, 0, 0);                                                        \
  } while (0)

__global__ __launch_bounds__(512, 2) void k_gemm2_hk(
    const u16* __restrict__ hid, const u16* __restrict__ w2t,
    float* __restrict__ out) {
  __shared__ __align__(16) u16 sA[2][256 * 64];
  __shared__ __align__(16) u16 sB[2][256 * 64];
  const int NT = INTER / 64;  // 88
  const int brow = blockIdx.y * 256, bcol = blockIdx.x * 256;

  const int tid = threadIdx.x, lane = tid & 63, wid = tid >> 6;
  const int wm = wid >> 2, wn = wid & 3;
  const int cb = lane & 15, hi = lane >> 4;
  const int srow = lane >> 3, schunk = lane & 7;

  f32x4 acc[8][4] = {};
  bf16x8 aF[4][2], bF[2][2];

  const u16* gA0 = hid + (size_t)brow * INTER;
  const u16* gA1 = gA0 + (size_t)128 * INTER;
  const u16* gB0 = w2t + (size_t)bcol * INTER;
  const u16* gB1 = w2t + (size_t)(bcol + 128) * INTER;

  // prologue: tile0 x4, then {A0,B1,A1}(t1). 14 loads; vmcnt(6) forces tile0.
  STAGE(sA[0], gA0, INTER, 0);
  STAGE(sB[0], gB0, INTER, 0);
  STAGE(sA[0] + HALF, gA1, INTER, 0);
  STAGE(sB[0] + HALF, gB1, INTER, 0);
  STAGE(sA[1], gA0, INTER, 1);
  STAGE(sB[1] + HALF, gB1, INTER, 1);
  STAGE(sA[1] + HALF, gA1, INTER, 1);
  __builtin_amdgcn_sched_barrier(0);
  asm volatile("s_waitcnt vmcnt(6)" ::: "memory");
  __builtin_amdgcn_s_barrier();

  for (int t = 0; t < NT; ++t) {
    u16* bufA = sA[t & 1];
    u16* bufB = sB[t & 1];
    u16* nbB = sB[(t & 1) ^ 1];
    const bool s1 = (t + 1 < NT), s2 = (t + 2 < NT);

    // P0: quad(0,0); stage B0(t+1) -> nbuf (slot freed at (t-1).P3)
    LOAD_A(bufA, 0); LOAD_B(bufB, 0);
    if (s1) STAGE(nbB, gB0, INTER, t + 1);
    __builtin_amdgcn_s_barrier();
    __builtin_amdgcn_s_setprio(1); MMA_Q(0, 0); __builtin_amdgcn_s_setprio(0);
    __builtin_amdgcn_s_barrier();

    // P1: quad(0,1) (aF kept); stage A0(t+2) -> buf.A0 (freed at P0)
    LOAD_B(bufB, 1);
    if (s2) STAGE(bufA, gA0, INTER, t + 2);
    __builtin_amdgcn_s_barrier();
    __builtin_amdgcn_s_setprio(1); MMA_Q(0, 1); __builtin_amdgcn_s_setprio(0);
    __builtin_amdgcn_s_barrier();

    // P2: quad(1,1) (bF kept); stage B1(t+2) -> buf.B1 (freed at P1)
    LOAD_A(bufA, 1);
    if (s2) STAGE(bufB + HALF, gB1, INTER, t + 2);
    __builtin_amdgcn_s_barrier();
    __builtin_amdgcn_s_setprio(1); MMA_Q(1, 1); __builtin_amdgcn_s_setprio(0);
    __builtin_amdgcn_s_barrier();

    // P3: quad(1,0) (aF kept, re-read B0); stage A1(t+2) -> buf.A1 (freed P2)
    LOAD_B(bufB, 0);
    if (s2) STAGE(bufA + HALF, gA1, INTER, t + 2);
    __builtin_amdgcn_s_barrier();
    __builtin_amdgcn_s_setprio(1); MMA_Q(1, 0); __builtin_amdgcn_s_setprio(0);
    __builtin_amdgcn_sched_barrier(0);
    if (s2)      asm volatile("s_waitcnt vmcnt(6)" ::: "memory");
    else if (s1) asm volatile("s_waitcnt vmcnt(0)" ::: "memory");
    __builtin_amdgcn_s_barrier();
  }

#pragma unroll
  for (int j = 0; j < 8; ++j)
#pragma unroll
    for (int n = 0; n < 4; ++n) {
      const int col = bcol + n * 64 + wn * 16 + cb;
#pragma unroll
      for (int i = 0; i < 4; ++i) {
        const int row = brow + j * 32 + wm * 16 + hi * 4 + i;
        out[(size_t)row * HID + col] = acc[j][n][i];
      }
    }
}

// ---------------- launch ----------------

extern "C" void kernel_launch(void* const* d_in, const int* in_sizes, int n_in,
                              void* d_out, int out_size, void* d_ws, size_t ws_size,
                              hipStream_t stream) {
  const float* x  = (const float*)d_in[0];   // [8192][2048]
  const float* w1 = (const float*)d_in[1];   // [2048][11264]
  const float* w2 = (const float*)d_in[2];   // [5632][2048]
  float* out = (float*)d_out;

  const size_t off_xb  = 0;                   // 33554432
  const size_t off_w1t = 33554432;            // +46137344
  const size_t off_w2t = off_w1t + 46137344;  // +23068672
  const size_t off_hid = off_w2t + 23068672;  // +92274688
  const size_t need    = off_hid + 92274688;
  if (ws_size < need) return;

  char* ws = (char*)d_ws;
  u16* xb  = (u16*)(ws + off_xb);
  u16* w1t = (u16*)(ws + off_w1t);
  u16* w2t = (u16*)(ws + off_w2t);
  u16* hid = (u16*)(ws + off_hid);

  k_cvt_x<<<TOKENS * HID / 8 / 256, 256, 0, stream>>>(x, xb);
  k_transpose64<<<dim3((2 * INTER) / 64, HID / 64), 256, 0, stream>>>(w1, w1t, HID, 2 * INTER);
  k_transpose64<<<dim3(HID / 64, INTER / 64), 256, 0, stream>>>(w2, w2t, INTER, HID);

  k_gemm1<<<dim3(INTER / 64, TOKENS / 128), 256, 0, stream>>>(xb, w1t, hid);
  k_gemm2_hk<<<dim3(HID / 256, TOKENS / 256), 512, 0, stream>>>(hid, w2t, out);
}